// Round 1
// baseline (1220.640 us; speedup 1.0000x reference)
//
#include <hip/hip_runtime.h>
#include <math.h>

#define BATCH 16
#define SEQ   2048
#define EMB   1024
#define HD    64
#define NROWS (BATCH*SEQ)

// ---------------- kernel 0: transpose weights into ws ----------------
// Wt[c192][e] = W_m[e][c],  c192 = m*64+c.  One-time 768 KiB.
__global__ void k_transpose_w(const float* __restrict__ Wq,
                              const float* __restrict__ Wk,
                              const float* __restrict__ Wv,
                              float* __restrict__ wt) {
    int idx  = blockIdx.x * 256 + threadIdx.x;   // 0 .. 192*1024-1
    int c192 = idx >> 10;
    int e    = idx & 1023;
    const float* W = (c192 < 64) ? Wq : (c192 < 128 ? Wk : Wv);
    int c = c192 & 63;
    wt[idx] = W[e * HD + c];
}

// ---------------- kernel 1: fused QKV projection ----------------
// [32768 x 1024] @ [1024 x 192]  (192 = q|k|v cols). Block: 64 rows x 192 cols.
// LDS-staged E-chunks of 32, 4x12 register blocking, float4 inner dot.
#define PEC 32
#define PXS 36   // x lds stride (floats); 36*4=144 B, 16B aligned
#define PWS 36

__global__ __launch_bounds__(256)
void k_qkv_proj(const float* __restrict__ x,
                const float* __restrict__ wt,
                float* __restrict__ qkv) {
    __shared__ float xls[64 * PXS];
    __shared__ float wls[192 * PWS];
    const int t    = threadIdx.x;
    const int row0 = blockIdx.x * 64;
    const int tr   = t >> 4;   // 0..15 -> rows tr*4..tr*4+3
    const int tc   = t & 15;   // 0..15 -> cols tc + 16*cc (cc<12) => 2-way-free LDS banks
    float acc[4][12];
    #pragma unroll
    for (int i = 0; i < 4; ++i)
        #pragma unroll
        for (int j = 0; j < 12; ++j) acc[i][j] = 0.f;

    for (int ch = 0; ch < EMB/PEC; ++ch) {
        const int e0 = ch * PEC;
        __syncthreads();
        #pragma unroll
        for (int i = 0; i < 2; ++i) {          // stage x: 64 rows x 8 quads
            int fidx = t + i*256;
            int r = fidx >> 3, q8 = fidx & 7;
            float4 v = *(const float4*)&x[(size_t)(row0 + r)*EMB + e0 + q8*4];
            *(float4*)&xls[r*PXS + q8*4] = v;
        }
        #pragma unroll
        for (int i = 0; i < 6; ++i) {          // stage wt: 192 rows x 8 quads
            int fidx = t + i*256;
            int c = fidx >> 3, q8 = fidx & 7;
            float4 v = *(const float4*)&wt[(size_t)c*EMB + e0 + q8*4];
            *(float4*)&wls[c*PWS + q8*4] = v;
        }
        __syncthreads();
        #pragma unroll
        for (int eq = 0; eq < PEC/4; ++eq) {
            float4 xv[4];
            #pragma unroll
            for (int rr = 0; rr < 4; ++rr)
                xv[rr] = *(const float4*)&xls[(tr*4+rr)*PXS + eq*4];
            #pragma unroll
            for (int cc = 0; cc < 12; ++cc) {
                float4 wv = *(const float4*)&wls[(tc + 16*cc)*PWS + eq*4];
                #pragma unroll
                for (int rr = 0; rr < 4; ++rr)
                    acc[rr][cc] += xv[rr].x*wv.x + xv[rr].y*wv.y
                                 + xv[rr].z*wv.z + xv[rr].w*wv.w;
            }
        }
    }
    // qkv layout: [3][NROWS][64]
    #pragma unroll
    for (int rr = 0; rr < 4; ++rr) {
        int row = row0 + tr*4 + rr;
        #pragma unroll
        for (int cc = 0; cc < 12; ++cc) {
            int c192 = tc + 16*cc;
            int m = c192 >> 6, c = c192 & 63;
            qkv[(size_t)m*NROWS*HD + (size_t)row*HD + c] = acc[rr][cc];
        }
    }
}

// ---------------- kernel 2: causal flash attention (fp32) ----------------
// grid: 16 batches * 64 q-tiles (32 rows); heavy (high-qt) tiles first.
// 4 waves x 8 rows. K staged transposed (stride 65: conflict-free reads+writes),
// V row-major stride 68, P via LDS for key->headdim transpose.
#define QB   32
#define KB   64
#define QLS  68
#define KTLS 65
#define VLS  68
#define PLS  64

__global__ __launch_bounds__(256)
void k_attn(const float* __restrict__ qg, const float* __restrict__ kg,
            const float* __restrict__ vg, float* __restrict__ out) {
    __shared__ float qls [QB * QLS];
    __shared__ float ktls[KB * KTLS];
    __shared__ float vls [KB * VLS];
    __shared__ float pls [QB * PLS];
    const int t    = threadIdx.x;
    const int lane = t & 63;
    const int w    = t >> 6;
    const int b    = blockIdx.x & (BATCH-1);
    const int qt   = (SEQ/QB - 1) - (blockIdx.x >> 4);  // descending work order
    const int row0 = qt * QB;                           // within batch
    const float* qb = qg + (size_t)b*SEQ*HD;
    const float* kb = kg + (size_t)b*SEQ*HD;
    const float* vb = vg + (size_t)b*SEQ*HD;

    #pragma unroll
    for (int i = 0; i < 2; ++i) {            // stage q tile (32 x 64)
        int fidx = t + i*256;
        int r = fidx >> 4, hq = fidx & 15;
        float4 v = *(const float4*)&qb[(size_t)(row0 + r)*HD + hq*4];
        *(float4*)&qls[r*QLS + hq*4] = v;
    }

    float outr[8], m_[8], l_[8];
    #pragma unroll
    for (int i = 0; i < 8; ++i) { outr[i]=0.f; m_[i]=-INFINITY; l_[i]=0.f; }

    const int nkt = (row0 + QB - 1)/KB + 1;
    for (int kt = 0; kt < nkt; ++kt) {
        const int k0 = kt * KB;
        __syncthreads();                      // prev tile's PV reads done
        #pragma unroll
        for (int i = 0; i < 4; ++i) {         // stage K (transposed) + V
            int fidx = t + i*256;
            int key = fidx >> 4, hq = fidx & 15;
            float4 kv = *(const float4*)&kb[(size_t)(k0 + key)*HD + hq*4];
            ktls[(hq*4+0)*KTLS + key] = kv.x;
            ktls[(hq*4+1)*KTLS + key] = kv.y;
            ktls[(hq*4+2)*KTLS + key] = kv.z;
            ktls[(hq*4+3)*KTLS + key] = kv.w;
            float4 vv = *(const float4*)&vb[(size_t)(k0 + key)*HD + hq*4];
            *(float4*)&vls[key*VLS + hq*4] = vv;
        }
        __syncthreads();

        // QK^T + online softmax: lane = key, 2 groups of 4 rows
        #pragma unroll
        for (int rg = 0; rg < 2; ++rg) {
            const int rl = w*8 + rg*4;
            float s[4] = {0.f, 0.f, 0.f, 0.f};
            for (int hq = 0; hq < 16; ++hq) {
                float k0v = ktls[(hq*4+0)*KTLS + lane];
                float k1v = ktls[(hq*4+1)*KTLS + lane];
                float k2v = ktls[(hq*4+2)*KTLS + lane];
                float k3v = ktls[(hq*4+3)*KTLS + lane];
                #pragma unroll
                for (int rr = 0; rr < 4; ++rr) {
                    float4 q4 = *(const float4*)&qls[(rl+rr)*QLS + hq*4];
                    s[rr] += q4.x*k0v + q4.y*k1v + q4.z*k2v + q4.w*k3v;
                }
            }
            #pragma unroll
            for (int rr = 0; rr < 4; ++rr) {
                float sv = s[rr] * 0.125f;                 // 1/sqrt(64)
                if (kt == nkt-1) {
                    int limit = row0 + rl + rr - k0;       // causal mask
                    if (lane > limit) sv = -INFINITY;
                }
                float mx = sv;
                #pragma unroll
                for (int off = 32; off > 0; off >>= 1)
                    mx = fmaxf(mx, __shfl_xor(mx, off));
                const int idx = rg*4 + rr;
                float mn   = fmaxf(m_[idx], mx);
                float corr = __expf(m_[idx] - mn);
                float p    = __expf(sv - mn);
                float ps = p;
                #pragma unroll
                for (int off = 32; off > 0; off >>= 1)
                    ps += __shfl_xor(ps, off);
                l_[idx]   = l_[idx]*corr + ps;
                m_[idx]   = mn;
                outr[idx] *= corr;
                pls[(w*8 + idx)*PLS + lane] = p;
            }
        }
        __syncthreads();                      // p visible cross-lane; V still valid

        // PV: lane = head dim
        #pragma unroll
        for (int kq = 0; kq < 16; ++kq) {
            float v0 = vls[(kq*4+0)*VLS + lane];
            float v1 = vls[(kq*4+1)*VLS + lane];
            float v2 = vls[(kq*4+2)*VLS + lane];
            float v3 = vls[(kq*4+3)*VLS + lane];
            #pragma unroll
            for (int r = 0; r < 8; ++r) {
                float4 p4 = *(const float4*)&pls[(w*8+r)*PLS + kq*4];
                outr[r] += p4.x*v0 + p4.y*v1 + p4.z*v2 + p4.w*v3;
            }
        }
    }
    #pragma unroll
    for (int r = 0; r < 8; ++r) {
        int row = row0 + w*8 + r;
        out[((size_t)b*SEQ + row)*HD + lane] = outr[r] / l_[r];
    }
}

extern "C" void kernel_launch(void* const* d_in, const int* in_sizes, int n_in,
                              void* d_out, int out_size, void* d_ws, size_t ws_size,
                              hipStream_t stream) {
    const float* x  = (const float*)d_in[0];
    const float* Wq = (const float*)d_in[1];
    const float* Wk = (const float*)d_in[2];
    const float* Wv = (const float*)d_in[3];
    float* out = (float*)d_out;
    float* ws  = (float*)d_ws;
    float* wt  = ws;                                   // 192*1024 floats
    float* qkv = ws + 192*1024;                        // 3 * NROWS * 64 floats (~24 MiB total)

    k_transpose_w<<<768, 256, 0, stream>>>(Wq, Wk, Wv, wt);
    k_qkv_proj  <<<NROWS/64, 256, 0, stream>>>(x, wt, qkv);
    k_attn      <<<BATCH*(SEQ/QB), 256, 0, stream>>>(qkv,
                                                     qkv + (size_t)NROWS*HD,
                                                     qkv + 2*(size_t)NROWS*HD,
                                                     out);
}

// Round 2
// 80.549 us; speedup vs baseline: 15.1541x; 15.1541x over previous
//
#include <hip/hip_runtime.h>
#include <math.h>

#define BATCH 16
#define SEQ   2048
#define EMB   1024
#define HD    64
#define NROWS (BATCH*SEQ)

typedef __attribute__((ext_vector_type(8))) short short8;
typedef __attribute__((ext_vector_type(4))) float f32x4;

// XOR-swizzle within a 128B row: permute 16B granules by (row&7). (T2 pattern)
#define SWZ(byte, row) ((byte) ^ (((row) & 7) << 4))

__device__ __forceinline__ ushort f2bf(float f) {
    union { float f; unsigned u; } c; c.f = f;
    return (ushort)((c.u + 0x7FFF + ((c.u >> 16) & 1)) >> 16);
}

// ------------- kernel 0: W[e][c] (fp32) -> wt16[c192][e] (bf16) -------------
__global__ void k_transpose_w(const float* __restrict__ Wq,
                              const float* __restrict__ Wk,
                              const float* __restrict__ Wv,
                              ushort* __restrict__ wt) {
    int idx  = blockIdx.x * 256 + threadIdx.x;   // 192*1024
    int c192 = idx >> 10;
    int e    = idx & 1023;
    const float* W = (c192 < 64) ? Wq : (c192 < 128 ? Wk : Wv);
    wt[idx] = f2bf(W[e * HD + (c192 & 63)]);
}

// ------------- kernel 1: QKV projection via MFMA (swapped form) -------------
// C^T[c192][row] = wt[c192][:] . x[row][:].  A = wt tile, B = x^T tile.
// Block: 64 rows x 192 cols, BK=64. LDS: x 64x64 bf16 (8KB) + wt 192x64 (24KB).
__global__ __launch_bounds__(256)
void k_qkv_proj(const float* __restrict__ x, const ushort* __restrict__ wt,
                ushort* __restrict__ qkv) {
    __shared__ short8 smem[(8192 + 24576) / 16];
    char* xls = (char*)smem;            // row r: byte r*128 + e*2   (swz)
    char* wls = (char*)smem + 8192;     // row c192: byte c*128 + e*2 (swz)
    const int t = threadIdx.x;
    const int lane = t & 63, w = t >> 6;
    const int l15 = lane & 15, lg = lane >> 4;
    const int row0 = blockIdx.x * 64;

    f32x4 acc[3][4];
    #pragma unroll
    for (int mi = 0; mi < 3; ++mi)
        #pragma unroll
        for (int n = 0; n < 4; ++n) acc[mi][n] = (f32x4){0.f,0.f,0.f,0.f};

    for (int ch = 0; ch < EMB / 64; ++ch) {
        __syncthreads();
        #pragma unroll
        for (int i = 0; i < 4; ++i) {            // stage x (fp32->bf16)
            int c = t + i * 256;                 // 1024 float4 chunks
            int r = c >> 4, f4 = c & 15;
            float4 v = *(const float4*)&x[(size_t)(row0 + r) * EMB + ch * 64 + f4 * 4];
            ushort4 bv;
            bv.x = f2bf(v.x); bv.y = f2bf(v.y); bv.z = f2bf(v.z); bv.w = f2bf(v.w);
            *(ushort4*)(xls + SWZ(r * 128 + f4 * 8, r)) = bv;
        }
        #pragma unroll
        for (int i = 0; i < 6; ++i) {            // stage wt
            int c = t + i * 256;                 // 1536 16B chunks
            int cr = c >> 3, j = c & 7;
            short8 v = *(const short8*)&wt[(size_t)cr * EMB + ch * 64 + j * 8];
            *(short8*)(wls + SWZ(cr * 128 + j * 16, cr)) = v;
        }
        __syncthreads();
        #pragma unroll
        for (int s = 0; s < 2; ++s) {
            short8 xf[4], wf[3];
            #pragma unroll
            for (int n = 0; n < 4; ++n) {
                int r = n * 16 + l15;
                xf[n] = *(short8*)(xls + SWZ(r * 128 + s * 64 + lg * 16, r));
            }
            #pragma unroll
            for (int mi = 0; mi < 3; ++mi) {
                int cr = w * 48 + mi * 16 + l15;
                wf[mi] = *(short8*)(wls + SWZ(cr * 128 + s * 64 + lg * 16, cr));
            }
            #pragma unroll
            for (int mi = 0; mi < 3; ++mi)
                #pragma unroll
                for (int n = 0; n < 4; ++n)
                    acc[mi][n] = __builtin_amdgcn_mfma_f32_16x16x32_bf16(
                        wf[mi], xf[n], acc[mi][n], 0, 0, 0);
        }
    }
    // D[c192][row]: col(lane&15)=row-in-tile, row-in-tile-of-D = c offset
    #pragma unroll
    for (int mi = 0; mi < 3; ++mi) {
        int cg0 = w * 48 + mi * 16 + 4 * lg;     // 4 consecutive c192
        int m = cg0 >> 6, c = cg0 & 63;
        float sc = (m == 0) ? 0.125f : 1.0f;     // fold softmax scale into Q
        #pragma unroll
        for (int n = 0; n < 4; ++n) {
            int row = row0 + n * 16 + l15;
            ushort4 o;
            o.x = f2bf(acc[mi][n][0] * sc);
            o.y = f2bf(acc[mi][n][1] * sc);
            o.z = f2bf(acc[mi][n][2] * sc);
            o.w = f2bf(acc[mi][n][3] * sc);
            *(ushort4*)&qkv[((size_t)m * NROWS + row) * HD + c] = o;
        }
    }
}

// ------------- kernel 2: V[b][key][hd] -> Vt[b][hd][key] (bf16) -------------
__global__ __launch_bounds__(256)
void k_vt(const ushort* __restrict__ v, ushort* __restrict__ vt) {
    __shared__ short8 sm[64 * 72 / 8];
    ushort* lds = (ushort*)sm;
    const int t = threadIdx.x;
    const int b = blockIdx.x >> 5, k0 = (blockIdx.x & 31) * 64;
    #pragma unroll
    for (int i = 0; i < 2; ++i) {
        int c = t + i * 256;
        int key = c >> 3, j = c & 7;
        short8 d = *(const short8*)&v[((size_t)b * SEQ + k0 + key) * HD + j * 8];
        #pragma unroll
        for (int e = 0; e < 8; ++e) lds[(j * 8 + e) * 72 + key] = (ushort)d[e];
    }
    __syncthreads();
    #pragma unroll
    for (int i = 0; i < 2; ++i) {
        int c = t + i * 256;
        int hd = c >> 3, j = c & 7;
        short8 d = *(short8*)&lds[hd * 72 + j * 8];
        *(short8*)&vt[((size_t)b * HD + hd) * SEQ + k0 + j * 8] = d;
    }
}

// ------------- kernel 3: causal flash attention via MFMA -------------
// QB=64 (wave w: 16 q-rows), KB=64. Swapped QK^T: S^T lane layout puts a full
// q-row in-lane (16 vals) + 2 shfl for row reduce. P -> per-wave swizzled LDS
// tile -> PV with pre-transposed V.
__global__ __launch_bounds__(256)
void k_attn(const ushort* __restrict__ q, const ushort* __restrict__ k,
            const ushort* __restrict__ vt, float* __restrict__ out) {
    __shared__ short8 smem[(8192 + 8192 + 8192) / 16];
    char* kls = (char*)smem;            // K  [key64][hd64]  swz
    char* vls = (char*)smem + 8192;     // Vt [hd64][key64]  swz
    char* pls = (char*)smem + 16384;    // P per-wave [16][64] swz
    const int t = threadIdx.x, lane = t & 63, w = t >> 6;
    const int l15 = lane & 15, lg = lane >> 4;
    const int b = blockIdx.x & 15, qt = 31 - (blockIdx.x >> 4);  // heavy first
    const int row0 = qt * 64;
    const int r0w = row0 + w * 16;
    const ushort* qb = q  + (size_t)b * SEQ * HD;
    const ushort* kb = k  + (size_t)b * SEQ * HD;
    const ushort* vb = vt + (size_t)b * HD * SEQ;
    char* pw = pls + w * 2048;

    short8 qf[2];                        // B-frag: row=l15, hd 8*lg.. contiguous
    #pragma unroll
    for (int s = 0; s < 2; ++s)
        qf[s] = *(const short8*)&qb[(size_t)(r0w + l15) * HD + s * 32 + lg * 8];

    f32x4 oacc[4];
    #pragma unroll
    for (int h = 0; h < 4; ++h) oacc[h] = (f32x4){0.f,0.f,0.f,0.f};
    float m_ = -INFINITY, l_ = 0.f;

    const int nkt = qt + 1;
    for (int kt = 0; kt < nkt; ++kt) {
        const int k0 = kt * 64;
        __syncthreads();                 // prior iter's K/Vt reads done
        #pragma unroll
        for (int i = 0; i < 2; ++i) {    // stage K + Vt
            int c = t + i * 256;
            int r = c >> 3, j = c & 7;
            short8 kv = *(const short8*)&kb[(size_t)(k0 + r) * HD + j * 8];
            *(short8*)(kls + SWZ(r * 128 + j * 16, r)) = kv;
            short8 vv = *(const short8*)&vb[(size_t)r * SEQ + k0 + j * 8];
            *(short8*)(vls + SWZ(r * 128 + j * 16, r)) = vv;
        }
        __syncthreads();

        // QK^T (swapped): D[key][qrow], lane holds qrow=l15, keys a*16+4*lg+r
        f32x4 sa[4];
        #pragma unroll
        for (int a = 0; a < 4; ++a) sa[a] = (f32x4){0.f,0.f,0.f,0.f};
        #pragma unroll
        for (int s = 0; s < 2; ++s)
            #pragma unroll
            for (int a = 0; a < 4; ++a) {
                int r = a * 16 + l15;
                short8 kf = *(short8*)(kls + SWZ(r * 128 + s * 64 + lg * 16, r));
                sa[a] = __builtin_amdgcn_mfma_f32_16x16x32_bf16(kf, qf[s], sa[a], 0, 0, 0);
            }

        if (kt == nkt - 1) {             // causal mask (only last k-step)
            int qrow = r0w + l15;
            #pragma unroll
            for (int a = 0; a < 4; ++a)
                #pragma unroll
                for (int r = 0; r < 4; ++r)
                    if (k0 + a * 16 + 4 * lg + r > qrow) sa[a][r] = -INFINITY;
        }

        // online softmax: row fully lane-local (16 vals) + 2 shfl
        float smax = -INFINITY;
        #pragma unroll
        for (int a = 0; a < 4; ++a)
            #pragma unroll
            for (int r = 0; r < 4; ++r) smax = fmaxf(smax, sa[a][r]);
        smax = fmaxf(smax, __shfl_xor(smax, 16));
        smax = fmaxf(smax, __shfl_xor(smax, 32));
        float mn   = fmaxf(m_, smax);
        float corr = __expf(m_ - mn);
        float p[16], ps = 0.f;
        #pragma unroll
        for (int a = 0; a < 4; ++a)
            #pragma unroll
            for (int r = 0; r < 4; ++r) {
                float pv = __expf(sa[a][r] - mn);
                p[a * 4 + r] = pv; ps += pv;
            }
        ps += __shfl_xor(ps, 16);
        ps += __shfl_xor(ps, 32);
        l_ = l_ * corr + ps;
        m_ = mn;
        #pragma unroll
        for (int h = 0; h < 4; ++h) oacc[h] *= corr;

        // P -> per-wave LDS (bf16, swizzled): row l15, keys a*16+4*lg..+3
        #pragma unroll
        for (int a = 0; a < 4; ++a) {
            ushort4 pb;
            pb.x = f2bf(p[a * 4 + 0]); pb.y = f2bf(p[a * 4 + 1]);
            pb.z = f2bf(p[a * 4 + 2]); pb.w = f2bf(p[a * 4 + 3]);
            *(ushort4*)(pw + SWZ(l15 * 128 + a * 32 + lg * 8, l15)) = pb;
        }

        // PV (swapped): out^T[hd][qrow] += Vt[hd][key] * P^T[key][qrow]
        #pragma unroll
        for (int c = 0; c < 2; ++c) {
            short8 pf = *(short8*)(pw + SWZ(l15 * 128 + c * 64 + lg * 16, l15));
            #pragma unroll
            for (int h = 0; h < 4; ++h) {
                int r = h * 16 + l15;
                short8 vf = *(short8*)(vls + SWZ(r * 128 + c * 64 + lg * 16, r));
                oacc[h] = __builtin_amdgcn_mfma_f32_16x16x32_bf16(vf, pf, oacc[h], 0, 0, 0);
            }
        }
    }

    float inv = 1.0f / l_;
    #pragma unroll
    for (int h = 0; h < 4; ++h)
        #pragma unroll
        for (int r = 0; r < 4; ++r) {
            int hd = h * 16 + 4 * lg + r;
            out[((size_t)b * SEQ + r0w + l15) * HD + hd] = oacc[h][r] * inv;
        }
}

extern "C" void kernel_launch(void* const* d_in, const int* in_sizes, int n_in,
                              void* d_out, int out_size, void* d_ws, size_t ws_size,
                              hipStream_t stream) {
    const float* x  = (const float*)d_in[0];
    const float* Wq = (const float*)d_in[1];
    const float* Wk = (const float*)d_in[2];
    const float* Wv = (const float*)d_in[3];
    float* out = (float*)d_out;
    ushort* ws = (ushort*)d_ws;
    ushort* wt16  = ws;                                  // 192*1024
    ushort* qkv16 = ws + 192 * 1024;                     // 3*NROWS*64
    ushort* vt16  = qkv16 + (size_t)3 * NROWS * HD;      // BATCH*64*2048

    k_transpose_w<<<768, 256, 0, stream>>>(Wq, Wk, Wv, wt16);
    k_qkv_proj  <<<NROWS / 64, 256, 0, stream>>>(x, wt16, qkv16);
    k_vt        <<<BATCH * (SEQ / 64), 256, 0, stream>>>(
                    qkv16 + (size_t)2 * NROWS * HD, vt16);
    k_attn      <<<BATCH * (SEQ / 64), 256, 0, stream>>>(
                    qkv16, qkv16 + (size_t)NROWS * HD, vt16, out);
}

// Round 3
// 72.344 us; speedup vs baseline: 16.8727x; 1.1134x over previous
//
#include <hip/hip_runtime.h>
#include <math.h>

#define BATCH 16
#define SEQ   2048
#define EMB   1024
#define HD    64
#define NROWS (BATCH*SEQ)

typedef __attribute__((ext_vector_type(8))) short short8;
typedef __attribute__((ext_vector_type(4))) float f32x4;

// XOR-swizzle 16B granules within a row (T2): 128B rows use row&7, 256B rows row&15
#define SWZ(byte, row)   ((byte) ^ (((row) & 7) << 4))
#define SWZ16(byte, row) ((byte) ^ (((row) & 15) << 4))

__device__ __forceinline__ ushort f2bf(float f) {
    union { float f; unsigned u; } c; c.f = f;
    return (ushort)((c.u + 0x7FFF + ((c.u >> 16) & 1)) >> 16);
}

// async global->LDS, 16B per lane; LDS dest = wave-uniform base + lane*16
__device__ __forceinline__ void gload_lds16(const void* g, void* l) {
    __builtin_amdgcn_global_load_lds(
        (const __attribute__((address_space(1))) void*)g,
        (__attribute__((address_space(3))) void*)l, 16, 0, 0);
}

// ------------- kernel 0: W[e][c] (fp32) -> wt16[c192][e] (bf16) -------------
__global__ void k_transpose_w(const float* __restrict__ Wq,
                              const float* __restrict__ Wk,
                              const float* __restrict__ Wv,
                              ushort* __restrict__ wt) {
    int idx  = blockIdx.x * 256 + threadIdx.x;   // 192*1024
    int c192 = idx >> 10;
    int e    = idx & 1023;
    const float* W = (c192 < 64) ? Wq : (c192 < 128 ? Wk : Wv);
    wt[idx] = f2bf(W[e * HD + (c192 & 63)]);
}

// ------------- kernel 1: QKV projection, double-buffered, V^T fused -------------
// Block: 64 rows x 192 cols, BK=64, 16 chunks. LDS 2 x (8KB x + 24KB wt) = 64KB.
// Q/K: D[c][row] via mfma(wf,xf). V: D[row][c] via mfma(xf,wf) -> V^T for free.
// Epilogue: LDS-transpose -> coalesced 16B stores. Q pre-scaled by 0.125*log2e.
__global__ __launch_bounds__(256)
void k_qkv_proj(const float* __restrict__ x, const ushort* __restrict__ wt,
                ushort* __restrict__ qkv, ushort* __restrict__ vt) {
    __shared__ short8 smem[65536 / 16];
    char* base = (char*)smem;
    const int t = threadIdx.x, lane = t & 63, w = t >> 6;
    const int l15 = lane & 15, lg = lane >> 4;
    const int row0 = blockIdx.x * 64;

    f32x4 acc[3][4];
    #pragma unroll
    for (int mi = 0; mi < 3; ++mi)
        #pragma unroll
        for (int n = 0; n < 4; ++n) acc[mi][n] = (f32x4){0.f, 0.f, 0.f, 0.f};

    float4 xr[2][2];

    auto issue_x = [&](int ch) {                 // global -> regs (fp32)
        #pragma unroll
        for (int i = 0; i < 2; ++i) {
            int fidx = t + i * 256;              // 512 granules of 16B (bf16)
            int r = fidx >> 3, j = fidx & 7;
            const float* src = &x[(size_t)(row0 + r) * EMB + ch * 64 + j * 8];
            xr[i][0] = *(const float4*)(src);
            xr[i][1] = *(const float4*)(src + 4);
        }
    };
    auto write_x = [&](int buf) {                // regs -> cvt -> LDS (swz)
        char* xb = base + buf * 32768;
        #pragma unroll
        for (int i = 0; i < 2; ++i) {
            int fidx = t + i * 256;
            int r = fidx >> 3, j = fidx & 7;
            short8 o;
            o[0] = (short)f2bf(xr[i][0].x); o[1] = (short)f2bf(xr[i][0].y);
            o[2] = (short)f2bf(xr[i][0].z); o[3] = (short)f2bf(xr[i][0].w);
            o[4] = (short)f2bf(xr[i][1].x); o[5] = (short)f2bf(xr[i][1].y);
            o[6] = (short)f2bf(xr[i][1].z); o[7] = (short)f2bf(xr[i][1].w);
            *(short8*)(xb + SWZ(r * 128 + j * 16, r)) = o;
        }
    };
    auto issue_w = [&](int ch, int buf) {        // global -> LDS DMA, pre-swz src
        char* wb = base + buf * 32768 + 8192;
        #pragma unroll
        for (int i = 0; i < 6; ++i) {
            int r = (w * 6 + i) * 8 + (lane >> 3);
            int j = (lane & 7) ^ (r & 7);
            gload_lds16(&wt[(size_t)r * EMB + ch * 64 + j * 8],
                        wb + (w * 6 + i) * 1024);
        }
    };
    auto compute = [&](int buf) {
        char* xb = base + buf * 32768;
        char* wb = base + buf * 32768 + 8192;
        #pragma unroll
        for (int s = 0; s < 2; ++s) {
            short8 xf[4], wf[3];
            #pragma unroll
            for (int n = 0; n < 4; ++n) {
                int r = n * 16 + l15;
                xf[n] = *(short8*)(xb + SWZ(r * 128 + s * 64 + lg * 16, r));
            }
            #pragma unroll
            for (int mi = 0; mi < 3; ++mi) {
                int cr = w * 48 + mi * 16 + l15;
                wf[mi] = *(short8*)(wb + SWZ(cr * 128 + s * 64 + lg * 16, cr));
            }
            __builtin_amdgcn_s_setprio(1);
            #pragma unroll
            for (int mi = 0; mi < 3; ++mi) {
                bool vsec = (w * 48 + mi * 16) >= 128;
                #pragma unroll
                for (int n = 0; n < 4; ++n)
                    acc[mi][n] = vsec
                        ? __builtin_amdgcn_mfma_f32_16x16x32_bf16(xf[n], wf[mi], acc[mi][n], 0, 0, 0)
                        : __builtin_amdgcn_mfma_f32_16x16x32_bf16(wf[mi], xf[n], acc[mi][n], 0, 0, 0);
            }
            __builtin_amdgcn_s_setprio(0);
        }
    };

    issue_x(0); issue_w(0, 0); write_x(0);
    __syncthreads();
    for (int ch = 0; ch < 16; ++ch) {
        int cur = ch & 1, nxt = cur ^ 1;
        if (ch < 15) { issue_w(ch + 1, nxt); issue_x(ch + 1); }
        compute(cur);
        if (ch < 15) write_x(nxt);
        __syncthreads();
    }

    // epilogue: transpose through LDS -> coalesced stores
    char* qkb = base;          // [64 xrow][128 c] bf16, 256B rows, SWZ16
    char* vtb = base + 16384;  // [64 hd][64 key] bf16, 128B rows, SWZ
    const float qscale = 0.125f * 1.44269504f;   // fold 1/sqrt(64) * log2(e)
    #pragma unroll
    for (int mi = 0; mi < 3; ++mi) {
        int cg0 = w * 48 + mi * 16;
        bool vsec = cg0 >= 128;
        #pragma unroll
        for (int n = 0; n < 4; ++n) {
            ushort4 o;
            if (!vsec) {
                float sc = (cg0 < 64) ? qscale : 1.0f;
                o.x = f2bf(acc[mi][n][0] * sc); o.y = f2bf(acc[mi][n][1] * sc);
                o.z = f2bf(acc[mi][n][2] * sc); o.w = f2bf(acc[mi][n][3] * sc);
                int xrow = n * 16 + l15, c = cg0 + lg * 4;
                *(ushort4*)(qkb + SWZ16(xrow * 256 + c * 2, xrow)) = o;
            } else {
                o.x = f2bf(acc[mi][n][0]); o.y = f2bf(acc[mi][n][1]);
                o.z = f2bf(acc[mi][n][2]); o.w = f2bf(acc[mi][n][3]);
                int hd = cg0 - 128 + l15, key = n * 16 + lg * 4;
                *(ushort4*)(vtb + SWZ(hd * 128 + key * 2, hd)) = o;
            }
        }
    }
    __syncthreads();
    const int b = row0 >> 11, r0b = row0 & 2047;
    #pragma unroll
    for (int i = 0; i < 4; ++i) {                // Q/K: 1024 granules
        int idx = t + i * 256;
        int r = idx >> 4, g = idx & 15;
        short8 v = *(short8*)(qkb + SWZ16(r * 256 + g * 16, r));
        int c0 = g * 8, m = c0 >> 6, c = c0 & 63;
        *(short8*)&qkv[((size_t)m * NROWS + row0 + r) * HD + c] = v;
    }
    #pragma unroll
    for (int i = 0; i < 2; ++i) {                // V^T: 512 granules
        int idx = t + i * 256;
        int hd = idx >> 3, g = idx & 7;
        short8 v = *(short8*)(vtb + SWZ(hd * 128 + g * 16, hd));
        *(short8*)&vt[((size_t)b * HD + hd) * SEQ + r0b + g * 8] = v;
    }
}

// ------------- kernel 2: causal flash attention, double-buffered -------------
// QB=64 (wave: 16 q-rows), KB=64. Swapped QK^T -> q-row lane-local softmax
// (exp2 domain, defer-max). K/V^T staged via global_load_lds (pre-swz src).
__global__ __launch_bounds__(256)
void k_attn(const ushort* __restrict__ q, const ushort* __restrict__ k,
            const ushort* __restrict__ vt, float* __restrict__ out) {
    __shared__ short8 smem[40960 / 16];
    char* base = (char*)smem;                    // 2 x (K 8KB + V 8KB)
    char* pls  = base + 32768;                   // P: 4 waves x 2KB
    const int t = threadIdx.x, lane = t & 63, w = t >> 6;
    const int l15 = lane & 15, lg = lane >> 4;
    const int b = blockIdx.x & 15, qt = 31 - (blockIdx.x >> 4);  // heavy first
    const int row0 = qt * 64, r0w = row0 + w * 16;
    const ushort* qb = q  + (size_t)b * SEQ * HD;
    const ushort* kb = k  + (size_t)b * SEQ * HD;
    const ushort* vb = vt + (size_t)b * HD * SEQ;
    char* pw = pls + w * 2048;

    short8 qf[2];
    #pragma unroll
    for (int s = 0; s < 2; ++s)
        qf[s] = *(const short8*)&qb[(size_t)(r0w + l15) * HD + s * 32 + lg * 8];

    f32x4 oacc[4];
    #pragma unroll
    for (int h = 0; h < 4; ++h) oacc[h] = (f32x4){0.f, 0.f, 0.f, 0.f};
    float m_ = -INFINITY, l_ = 0.f;

    auto stage = [&](int kt, int buf) {
        char* kbuf = base + buf * 16384;
        char* vbuf = kbuf + 8192;
        int k0 = kt * 64;
        #pragma unroll
        for (int i = 0; i < 2; ++i) {
            int r = (w * 2 + i) * 8 + (lane >> 3);
            int j = (lane & 7) ^ (r & 7);
            gload_lds16(&kb[(size_t)(k0 + r) * HD + j * 8], kbuf + (w * 2 + i) * 1024);
            gload_lds16(&vb[(size_t)r * SEQ + k0 + j * 8],  vbuf + (w * 2 + i) * 1024);
        }
    };

    const int nkt = qt + 1;
    stage(0, 0);
    __syncthreads();
    for (int kt = 0; kt < nkt; ++kt) {
        int cur = kt & 1;
        if (kt + 1 < nkt) stage(kt + 1, cur ^ 1);
        char* kls = base + cur * 16384;
        char* vls = kls + 8192;
        int k0 = kt * 64;

        f32x4 sa[4];
        #pragma unroll
        for (int a = 0; a < 4; ++a) sa[a] = (f32x4){0.f, 0.f, 0.f, 0.f};
        __builtin_amdgcn_s_setprio(1);
        #pragma unroll
        for (int s = 0; s < 2; ++s)
            #pragma unroll
            for (int a = 0; a < 4; ++a) {
                int r = a * 16 + l15;
                short8 kf = *(short8*)(kls + SWZ(r * 128 + s * 64 + lg * 16, r));
                sa[a] = __builtin_amdgcn_mfma_f32_16x16x32_bf16(kf, qf[s], sa[a], 0, 0, 0);
            }
        __builtin_amdgcn_s_setprio(0);

        if (kt == nkt - 1) {                     // causal mask
            int qrow = r0w + l15;
            #pragma unroll
            for (int a = 0; a < 4; ++a)
                #pragma unroll
                for (int r = 0; r < 4; ++r)
                    if (k0 + a * 16 + lg * 4 + r > qrow) sa[a][r] = -INFINITY;
        }

        // online softmax in exp2 domain; row fully lane-local + 2 shfl
        float smax = -INFINITY;
        #pragma unroll
        for (int a = 0; a < 4; ++a)
            #pragma unroll
            for (int r = 0; r < 4; ++r) smax = fmaxf(smax, sa[a][r]);
        smax = fmaxf(smax, __shfl_xor(smax, 16));
        smax = fmaxf(smax, __shfl_xor(smax, 32));
        if (!__all(smax - m_ <= 8.0f)) {         // T13 defer-max
            float mn   = fmaxf(m_, smax);
            float corr = __builtin_amdgcn_exp2f(m_ - mn);
            l_ *= corr;
            #pragma unroll
            for (int h = 0; h < 4; ++h) oacc[h] *= corr;
            m_ = mn;
        }
        float p[16], ps = 0.f;
        #pragma unroll
        for (int a = 0; a < 4; ++a)
            #pragma unroll
            for (int r = 0; r < 4; ++r) {
                float pv = __builtin_amdgcn_exp2f(sa[a][r] - m_);
                p[a * 4 + r] = pv; ps += pv;
            }
        ps += __shfl_xor(ps, 16);
        ps += __shfl_xor(ps, 32);
        l_ += ps;

        #pragma unroll
        for (int a = 0; a < 4; ++a) {            // P -> per-wave LDS (swz)
            ushort4 pb;
            pb.x = f2bf(p[a * 4 + 0]); pb.y = f2bf(p[a * 4 + 1]);
            pb.z = f2bf(p[a * 4 + 2]); pb.w = f2bf(p[a * 4 + 3]);
            *(ushort4*)(pw + SWZ(l15 * 128 + a * 32 + lg * 8, l15)) = pb;
        }

        __builtin_amdgcn_s_setprio(1);
        #pragma unroll
        for (int c = 0; c < 2; ++c) {            // PV
            short8 pf = *(short8*)(pw + SWZ(l15 * 128 + c * 64 + lg * 16, l15));
            #pragma unroll
            for (int h = 0; h < 4; ++h) {
                int r = h * 16 + l15;
                short8 vf = *(short8*)(vls + SWZ(r * 128 + c * 64 + lg * 16, r));
                oacc[h] = __builtin_amdgcn_mfma_f32_16x16x32_bf16(vf, pf, oacc[h], 0, 0, 0);
            }
        }
        __builtin_amdgcn_s_setprio(0);
        __syncthreads();
    }

    // epilogue: out via LDS transpose -> coalesced float4 stores
    float inv = 1.0f / l_;
    #pragma unroll
    for (int h = 0; h < 4; ++h) {
        f32x4 v = oacc[h] * inv;
        int qr = w * 16 + l15;
        *(f32x4*)(base + SWZ16(qr * 256 + h * 64 + lg * 16, qr)) = v;
    }
    __syncthreads();
    #pragma unroll
    for (int i = 0; i < 4; ++i) {
        int idx = t + i * 256;
        int r = idx >> 4, g = idx & 15;
        f32x4 v = *(f32x4*)(base + SWZ16(r * 256 + g * 16, r));
        *(f32x4*)&out[((size_t)b * SEQ + row0 + r) * HD + g * 4] = v;
    }
}

extern "C" void kernel_launch(void* const* d_in, const int* in_sizes, int n_in,
                              void* d_out, int out_size, void* d_ws, size_t ws_size,
                              hipStream_t stream) {
    const float* x  = (const float*)d_in[0];
    const float* Wq = (const float*)d_in[1];
    const float* Wk = (const float*)d_in[2];
    const float* Wv = (const float*)d_in[3];
    float* out = (float*)d_out;
    ushort* ws = (ushort*)d_ws;
    ushort* wt16 = ws;                                   // 192*1024
    ushort* qk16 = ws + 192 * 1024;                      // 2*NROWS*64 (Q,K)
    ushort* vt16 = qk16 + (size_t)2 * NROWS * HD;        // BATCH*64*2048

    k_transpose_w<<<768, 256, 0, stream>>>(Wq, Wk, Wv, wt16);
    k_qkv_proj  <<<NROWS / 64, 256, 0, stream>>>(x, wt16, qk16, vt16);
    k_attn      <<<BATCH * (SEQ / 64), 256, 0, stream>>>(
                    qk16, qk16 + (size_t)NROWS * HD, vt16, out);
}

// Round 4
// 70.416 us; speedup vs baseline: 17.3346x; 1.0274x over previous
//
#include <hip/hip_runtime.h>
#include <math.h>

#define BATCH 16
#define SEQ   2048
#define EMB   1024
#define HD    64
#define NROWS (BATCH*SEQ)

typedef __attribute__((ext_vector_type(8))) short short8;
typedef __attribute__((ext_vector_type(4))) float f32x4;

// XOR-swizzle 16B granules within a row (T2): 128B rows use row&7, 256B rows row&15
#define SWZ(byte, row)   ((byte) ^ (((row) & 7) << 4))
#define SWZ16(byte, row) ((byte) ^ (((row) & 15) << 4))

__device__ __forceinline__ ushort f2bf(float f) {
    union { float f; unsigned u; } c; c.f = f;
    return (ushort)((c.u + 0x7FFF + ((c.u >> 16) & 1)) >> 16);
}

// async global->LDS, 16B per lane; LDS dest = wave-uniform base + lane*16
__device__ __forceinline__ void gload_lds16(const void* g, void* l) {
    __builtin_amdgcn_global_load_lds(
        (const __attribute__((address_space(1))) void*)g,
        (__attribute__((address_space(3))) void*)l, 16, 0, 0);
}

// ------------- kernel 0: W[e][c] (fp32) -> wt16[c192][e] (bf16) -------------
__global__ void k_transpose_w(const float* __restrict__ Wq,
                              const float* __restrict__ Wk,
                              const float* __restrict__ Wv,
                              ushort* __restrict__ wt) {
    int idx  = blockIdx.x * 256 + threadIdx.x;   // 192*1024
    int c192 = idx >> 10;
    int e    = idx & 1023;
    const float* W = (c192 < 64) ? Wq : (c192 < 128 ? Wk : Wv);
    wt[idx] = f2bf(W[e * HD + (c192 & 63)]);
}

// ------------- kernel 1: QKV projection, double-buffered, V^T fused -------------
// (unchanged from round 3 — sits at its x-read HBM floor)
__global__ __launch_bounds__(256)
void k_qkv_proj(const float* __restrict__ x, const ushort* __restrict__ wt,
                ushort* __restrict__ qkv, ushort* __restrict__ vt) {
    __shared__ short8 smem[65536 / 16];
    char* base = (char*)smem;
    const int t = threadIdx.x, lane = t & 63, w = t >> 6;
    const int l15 = lane & 15, lg = lane >> 4;
    const int row0 = blockIdx.x * 64;

    f32x4 acc[3][4];
    #pragma unroll
    for (int mi = 0; mi < 3; ++mi)
        #pragma unroll
        for (int n = 0; n < 4; ++n) acc[mi][n] = (f32x4){0.f, 0.f, 0.f, 0.f};

    float4 xr[2][2];

    auto issue_x = [&](int ch) {
        #pragma unroll
        for (int i = 0; i < 2; ++i) {
            int fidx = t + i * 256;
            int r = fidx >> 3, j = fidx & 7;
            const float* src = &x[(size_t)(row0 + r) * EMB + ch * 64 + j * 8];
            xr[i][0] = *(const float4*)(src);
            xr[i][1] = *(const float4*)(src + 4);
        }
    };
    auto write_x = [&](int buf) {
        char* xb = base + buf * 32768;
        #pragma unroll
        for (int i = 0; i < 2; ++i) {
            int fidx = t + i * 256;
            int r = fidx >> 3, j = fidx & 7;
            short8 o;
            o[0] = (short)f2bf(xr[i][0].x); o[1] = (short)f2bf(xr[i][0].y);
            o[2] = (short)f2bf(xr[i][0].z); o[3] = (short)f2bf(xr[i][0].w);
            o[4] = (short)f2bf(xr[i][1].x); o[5] = (short)f2bf(xr[i][1].y);
            o[6] = (short)f2bf(xr[i][1].z); o[7] = (short)f2bf(xr[i][1].w);
            *(short8*)(xb + SWZ(r * 128 + j * 16, r)) = o;
        }
    };
    auto issue_w = [&](int ch, int buf) {
        char* wb = base + buf * 32768 + 8192;
        #pragma unroll
        for (int i = 0; i < 6; ++i) {
            int r = (w * 6 + i) * 8 + (lane >> 3);
            int j = (lane & 7) ^ (r & 7);
            gload_lds16(&wt[(size_t)r * EMB + ch * 64 + j * 8],
                        wb + (w * 6 + i) * 1024);
        }
    };
    auto compute = [&](int buf) {
        char* xb = base + buf * 32768;
        char* wb = base + buf * 32768 + 8192;
        #pragma unroll
        for (int s = 0; s < 2; ++s) {
            short8 xf[4], wf[3];
            #pragma unroll
            for (int n = 0; n < 4; ++n) {
                int r = n * 16 + l15;
                xf[n] = *(short8*)(xb + SWZ(r * 128 + s * 64 + lg * 16, r));
            }
            #pragma unroll
            for (int mi = 0; mi < 3; ++mi) {
                int cr = w * 48 + mi * 16 + l15;
                wf[mi] = *(short8*)(wb + SWZ(cr * 128 + s * 64 + lg * 16, cr));
            }
            __builtin_amdgcn_s_setprio(1);
            #pragma unroll
            for (int mi = 0; mi < 3; ++mi) {
                bool vsec = (w * 48 + mi * 16) >= 128;
                #pragma unroll
                for (int n = 0; n < 4; ++n)
                    acc[mi][n] = vsec
                        ? __builtin_amdgcn_mfma_f32_16x16x32_bf16(xf[n], wf[mi], acc[mi][n], 0, 0, 0)
                        : __builtin_amdgcn_mfma_f32_16x16x32_bf16(wf[mi], xf[n], acc[mi][n], 0, 0, 0);
            }
            __builtin_amdgcn_s_setprio(0);
        }
    };

    issue_x(0); issue_w(0, 0); write_x(0);
    __syncthreads();
    for (int ch = 0; ch < 16; ++ch) {
        int cur = ch & 1, nxt = cur ^ 1;
        if (ch < 15) { issue_w(ch + 1, nxt); issue_x(ch + 1); }
        compute(cur);
        if (ch < 15) write_x(nxt);
        __syncthreads();
    }

    char* qkb = base;
    char* vtb = base + 16384;
    const float qscale = 0.125f * 1.44269504f;
    #pragma unroll
    for (int mi = 0; mi < 3; ++mi) {
        int cg0 = w * 48 + mi * 16;
        bool vsec = cg0 >= 128;
        #pragma unroll
        for (int n = 0; n < 4; ++n) {
            ushort4 o;
            if (!vsec) {
                float sc = (cg0 < 64) ? qscale : 1.0f;
                o.x = f2bf(acc[mi][n][0] * sc); o.y = f2bf(acc[mi][n][1] * sc);
                o.z = f2bf(acc[mi][n][2] * sc); o.w = f2bf(acc[mi][n][3] * sc);
                int xrow = n * 16 + l15, c = cg0 + lg * 4;
                *(ushort4*)(qkb + SWZ16(xrow * 256 + c * 2, xrow)) = o;
            } else {
                o.x = f2bf(acc[mi][n][0]); o.y = f2bf(acc[mi][n][1]);
                o.z = f2bf(acc[mi][n][2]); o.w = f2bf(acc[mi][n][3]);
                int hd = cg0 - 128 + l15, key = n * 16 + lg * 4;
                *(ushort4*)(vtb + SWZ(hd * 128 + key * 2, hd)) = o;
            }
        }
    }
    __syncthreads();
    const int b = row0 >> 11, r0b = row0 & 2047;
    #pragma unroll
    for (int i = 0; i < 4; ++i) {
        int idx = t + i * 256;
        int r = idx >> 4, g = idx & 15;
        short8 v = *(short8*)(qkb + SWZ16(r * 256 + g * 16, r));
        int c0 = g * 8, m = c0 >> 6, c = c0 & 63;
        *(short8*)&qkv[((size_t)m * NROWS + row0 + r) * HD + c] = v;
    }
    #pragma unroll
    for (int i = 0; i < 2; ++i) {
        int idx = t + i * 256;
        int hd = idx >> 3, g = idx & 7;
        short8 v = *(short8*)(vtb + SWZ(hd * 128 + g * 16, hd));
        *(short8*)&vt[((size_t)b * HD + hd) * SEQ + r0b + g * 8] = v;
    }
}

// ------------- kernel 2: causal flash attention, KB=128 pair-steps -------------
// QB=64 (wave: 16 q-rows), 128 keys per iteration (two fused 64-key subtiles):
// halves barrier/softmax-reduce count, doubles QK MFMA ILP (16 indep chains).
// K buf [128][64] bf16 (SWZ), V^T buf [64][128] bf16 (SWZ16), double-buffered.
__global__ __launch_bounds__(256)
void k_attn(const ushort* __restrict__ q, const ushort* __restrict__ k,
            const ushort* __restrict__ vt, float* __restrict__ out) {
    __shared__ short8 smem[81920 / 16];
    char* base = (char*)smem;                    // 2 x (K 16KB + V 16KB)
    char* pls  = base + 65536;                   // P: 4 waves x 4KB ([16][128] bf16)
    const int t = threadIdx.x, lane = t & 63, w = t >> 6;
    const int l15 = lane & 15, lg = lane >> 4;
    const int b = blockIdx.x & 15, qt = 31 - (blockIdx.x >> 4);  // heavy first
    const int row0 = qt * 64, r0w = row0 + w * 16;
    const ushort* qb = q  + (size_t)b * SEQ * HD;
    const ushort* kb = k  + (size_t)b * SEQ * HD;
    const ushort* vb = vt + (size_t)b * HD * SEQ;
    char* pw = pls + w * 4096;

    short8 qf[2];
    #pragma unroll
    for (int s = 0; s < 2; ++s)
        qf[s] = *(const short8*)&qb[(size_t)(r0w + l15) * HD + s * 32 + lg * 8];

    f32x4 oacc[4];
    #pragma unroll
    for (int h = 0; h < 4; ++h) oacc[h] = (f32x4){0.f, 0.f, 0.f, 0.f};
    float m_ = -INFINITY, l_ = 0.f;

    // stage 128 keys: K [128 key][64 hd] rows 128B, V [64 hd][128 key] rows 256B
    auto stage = [&](int kt, int buf) {
        char* kbuf = base + buf * 32768;
        char* vbuf = kbuf + 16384;
        int k0 = kt * 128;
        #pragma unroll
        for (int g = 0; g < 4; ++g) {
            int rk = w * 32 + g * 8 + (lane >> 3);          // key row 0..127
            int jk = (lane & 7) ^ (rk & 7);
            gload_lds16(&kb[(size_t)(k0 + rk) * HD + jk * 8],
                        kbuf + (w * 4 + g) * 1024);
            int rv = w * 16 + g * 4 + (lane >> 4);          // hd row 0..63
            int jv = (lane & 15) ^ (rv & 15);
            gload_lds16(&vb[(size_t)rv * SEQ + k0 + jv * 8],
                        vbuf + (w * 4 + g) * 1024);
        }
    };

    const int npair = (qt + 2) >> 1;             // pairs*128 <= 2048 always
    stage(0, 0);
    __syncthreads();
    for (int kt = 0; kt < npair; ++kt) {
        int cur = kt & 1;
        if (kt + 1 < npair) stage(kt + 1, cur ^ 1);
        char* kls = base + cur * 32768;
        char* vls = kls + 16384;
        int k0 = kt * 128;

        // QK^T over 128 keys: 16 independent MFMA chains
        f32x4 sa[8];
        #pragma unroll
        for (int a = 0; a < 8; ++a) sa[a] = (f32x4){0.f, 0.f, 0.f, 0.f};
        __builtin_amdgcn_s_setprio(1);
        #pragma unroll
        for (int s = 0; s < 2; ++s)
            #pragma unroll
            for (int a = 0; a < 8; ++a) {
                int r = a * 16 + l15;
                short8 kf = *(short8*)(kls + SWZ(r * 128 + s * 64 + lg * 16, r));
                sa[a] = __builtin_amdgcn_mfma_f32_16x16x32_bf16(kf, qf[s], sa[a], 0, 0, 0);
            }
        __builtin_amdgcn_s_setprio(0);

        if (kt == npair - 1) {                   // causal mask (last pair only)
            int qrow = r0w + l15;
            #pragma unroll
            for (int a = 0; a < 8; ++a)
                #pragma unroll
                for (int r = 0; r < 4; ++r)
                    if (k0 + a * 16 + lg * 4 + r > qrow) sa[a][r] = -INFINITY;
        }

        // online softmax (exp2 domain), one reduce pair per 128 keys
        float smax = -INFINITY;
        #pragma unroll
        for (int a = 0; a < 8; ++a)
            #pragma unroll
            for (int r = 0; r < 4; ++r) smax = fmaxf(smax, sa[a][r]);
        smax = fmaxf(smax, __shfl_xor(smax, 16));
        smax = fmaxf(smax, __shfl_xor(smax, 32));
        if (!__all(smax - m_ <= 8.0f)) {         // T13 defer-max
            float mn   = fmaxf(m_, smax);
            float corr = __builtin_amdgcn_exp2f(m_ - mn);
            l_ *= corr;
            #pragma unroll
            for (int h = 0; h < 4; ++h) oacc[h] *= corr;
            m_ = mn;
        }
        float p[32], ps = 0.f;
        #pragma unroll
        for (int a = 0; a < 8; ++a)
            #pragma unroll
            for (int r = 0; r < 4; ++r) {
                float pv = __builtin_amdgcn_exp2f(sa[a][r] - m_);
                p[a * 4 + r] = pv; ps += pv;
            }
        ps += __shfl_xor(ps, 16);
        ps += __shfl_xor(ps, 32);
        l_ += ps;

        #pragma unroll
        for (int a = 0; a < 8; ++a) {            // P -> per-wave LDS [16][128]
            ushort4 pb;
            pb.x = f2bf(p[a * 4 + 0]); pb.y = f2bf(p[a * 4 + 1]);
            pb.z = f2bf(p[a * 4 + 2]); pb.w = f2bf(p[a * 4 + 3]);
            *(ushort4*)(pw + SWZ16(l15 * 256 + a * 32 + lg * 8, l15)) = pb;
        }

        __builtin_amdgcn_s_setprio(1);
        #pragma unroll
        for (int ki = 0; ki < 4; ++ki) {         // PV over 128 keys
            short8 pf = *(short8*)(pw + SWZ16(l15 * 256 + ki * 64 + lg * 16, l15));
            #pragma unroll
            for (int h = 0; h < 4; ++h) {
                int rr = h * 16 + l15;
                short8 vf = *(short8*)(vls + SWZ16(rr * 256 + ki * 64 + lg * 16, rr));
                oacc[h] = __builtin_amdgcn_mfma_f32_16x16x32_bf16(vf, pf, oacc[h], 0, 0, 0);
            }
        }
        __builtin_amdgcn_s_setprio(0);
        __syncthreads();                         // bufs free for next stage
    }

    // epilogue: out via LDS transpose -> coalesced float4 stores
    float inv = 1.0f / l_;
    #pragma unroll
    for (int h = 0; h < 4; ++h) {
        f32x4 v = oacc[h] * inv;
        int qr = w * 16 + l15;
        *(f32x4*)(base + SWZ16(qr * 256 + h * 64 + lg * 16, qr)) = v;
    }
    __syncthreads();
    #pragma unroll
    for (int i = 0; i < 4; ++i) {
        int idx = t + i * 256;
        int r = idx >> 4, g = idx & 15;
        f32x4 v = *(f32x4*)(base + SWZ16(r * 256 + g * 16, r));
        *(f32x4*)&out[((size_t)b * SEQ + row0 + r) * HD + g * 4] = v;
    }
}

extern "C" void kernel_launch(void* const* d_in, const int* in_sizes, int n_in,
                              void* d_out, int out_size, void* d_ws, size_t ws_size,
                              hipStream_t stream) {
    const float* x  = (const float*)d_in[0];
    const float* Wq = (const float*)d_in[1];
    const float* Wk = (const float*)d_in[2];
    const float* Wv = (const float*)d_in[3];
    float* out = (float*)d_out;
    ushort* ws = (ushort*)d_ws;
    ushort* wt16 = ws;                                   // 192*1024
    ushort* qk16 = ws + 192 * 1024;                      // 2*NROWS*64 (Q,K)
    ushort* vt16 = qk16 + (size_t)2 * NROWS * HD;        // BATCH*64*2048

    k_transpose_w<<<768, 256, 0, stream>>>(Wq, Wk, Wv, wt16);
    k_qkv_proj  <<<NROWS / 64, 256, 0, stream>>>(x, wt16, qk16, vt16);
    k_attn      <<<BATCH * (SEQ / 64), 256, 0, stream>>>(
                    qk16, qk16 + (size_t)NROWS * HD, vt16, out);
}

// Round 5
// 68.749 us; speedup vs baseline: 17.7549x; 1.0242x over previous
//
#include <hip/hip_runtime.h>
#include <math.h>

#define BATCH 16
#define SEQ   2048
#define EMB   1024
#define HD    64
#define NROWS (BATCH*SEQ)

typedef __attribute__((ext_vector_type(8))) short short8;
typedef __attribute__((ext_vector_type(4))) float f32x4;

// XOR-swizzle 16B granules within a row (T2): 128B rows use row&7, 256B rows row&15
#define SWZ(byte, row)   ((byte) ^ (((row) & 7) << 4))
#define SWZ16(byte, row) ((byte) ^ (((row) & 15) << 4))

__device__ __forceinline__ ushort f2bf(float f) {
    union { float f; unsigned u; } c; c.f = f;
    return (ushort)((c.u + 0x7FFF + ((c.u >> 16) & 1)) >> 16);
}

// async global->LDS, 16B per lane; LDS dest = wave-uniform base + lane*16
__device__ __forceinline__ void gload_lds16(const void* g, void* l) {
    __builtin_amdgcn_global_load_lds(
        (const __attribute__((address_space(1))) void*)g,
        (__attribute__((address_space(3))) void*)l, 16, 0, 0);
}

// ------------- kernel 0: W[e][c] (fp32) -> wt16[c192][e] (bf16) -------------
__global__ void k_transpose_w(const float* __restrict__ Wq,
                              const float* __restrict__ Wk,
                              const float* __restrict__ Wv,
                              ushort* __restrict__ wt) {
    int idx  = blockIdx.x * 256 + threadIdx.x;   // 192*1024
    int c192 = idx >> 10;
    int e    = idx & 1023;
    const float* W = (c192 < 64) ? Wq : (c192 < 128 ? Wk : Wv);
    wt[idx] = f2bf(W[e * HD + (c192 & 63)]);
}

// ------------- kernel 1: QKV projection v2 -------------
// Row-partitioned waves: wave w owns 16 x-rows, computes all 192 cols.
// x: direct global fp32 reads (coalesced 16x128B, read once), cvt at use.
// wt: LDS double-buffered via global_load_lds (pre-swizzled source).
// Q/K: D[c][row] = mfma(wf,xf);  V: D[key][hd] = mfma(xf,wf) -> V^T free.
__global__ __launch_bounds__(256)
void k_qkv_proj(const float* __restrict__ x, const ushort* __restrict__ wt,
                ushort* __restrict__ qkv, ushort* __restrict__ vt) {
    __shared__ short8 smem[49152 / 16];
    char* base = (char*)smem;                    // 2 x 24KB wt buffers
    const int t = threadIdx.x, lane = t & 63, w = t >> 6;
    const int l15 = lane & 15, lg = lane >> 4;
    const int row0 = blockIdx.x * 64;
    const float* xrowp = x + (size_t)(row0 + w * 16 + l15) * EMB;  // lane's x row

    f32x4 acc[12];
    #pragma unroll
    for (int mi = 0; mi < 12; ++mi) acc[mi] = (f32x4){0.f, 0.f, 0.f, 0.f};

    float4 xc[4], xn[4];                         // cur/next chunk: 2 s x 2 float4

    auto stage_w = [&](int ch, int buf) {
        char* wb = base + buf * 24576;
        #pragma unroll
        for (int i = 0; i < 6; ++i) {
            int r = (w * 6 + i) * 8 + (lane >> 3);
            int j = (lane & 7) ^ (r & 7);
            gload_lds16(&wt[(size_t)r * EMB + ch * 64 + j * 8],
                        wb + (w * 6 + i) * 1024);
        }
    };
    auto load_x = [&](int ch, float4* xr) {
        #pragma unroll
        for (int s = 0; s < 2; ++s) {
            const float* p = xrowp + ch * 64 + s * 32 + lg * 8;
            xr[s * 2 + 0] = *(const float4*)(p);
            xr[s * 2 + 1] = *(const float4*)(p + 4);
        }
    };

    stage_w(0, 0); load_x(0, xc);
    __syncthreads();
    for (int ch = 0; ch < 16; ++ch) {
        int cur = ch & 1;
        if (ch < 15) { stage_w(ch + 1, cur ^ 1); load_x(ch + 1, xn); }
        char* wb = base + cur * 24576;
        #pragma unroll
        for (int s = 0; s < 2; ++s) {
            const float* xp = (const float*)&xc[s * 2];
            short8 xf;
            #pragma unroll
            for (int e = 0; e < 8; ++e) xf[e] = (short)f2bf(xp[e]);
            __builtin_amdgcn_s_setprio(1);
            #pragma unroll
            for (int mi = 0; mi < 12; ++mi) {
                int cr = mi * 16 + l15;
                short8 wf = *(short8*)(wb + SWZ(cr * 128 + s * 64 + lg * 16, cr));
                acc[mi] = (mi < 8)
                    ? __builtin_amdgcn_mfma_f32_16x16x32_bf16(wf, xf, acc[mi], 0, 0, 0)
                    : __builtin_amdgcn_mfma_f32_16x16x32_bf16(xf, wf, acc[mi], 0, 0, 0);
            }
            __builtin_amdgcn_s_setprio(0);
        }
        if (ch < 15) {
            #pragma unroll
            for (int i = 0; i < 4; ++i) xc[i] = xn[i];
        }
        __syncthreads();
    }

    // epilogue: LDS transposes -> coalesced stores (reuse wt LDS)
    char* qkb = base;          // [64 xrow][128 c] bf16, 256B rows, SWZ16
    char* vtb = base + 16384;  // [64 hd][64 key] bf16, 128B rows, SWZ
    const float qscale = 0.125f * 1.44269504f;   // fold 1/sqrt(64)*log2(e) into Q
    #pragma unroll
    for (int mi = 0; mi < 12; ++mi) {
        ushort4 o;
        if (mi < 8) {                            // Q/K: rows of D = c, col = xrow
            float sc = (mi < 4) ? qscale : 1.0f;
            o.x = f2bf(acc[mi][0] * sc); o.y = f2bf(acc[mi][1] * sc);
            o.z = f2bf(acc[mi][2] * sc); o.w = f2bf(acc[mi][3] * sc);
            int xrow = w * 16 + l15, c = mi * 16 + lg * 4;
            *(ushort4*)(qkb + SWZ16(xrow * 256 + c * 2, xrow)) = o;
        } else {                                 // V: D[key][hd] (already V^T)
            o.x = f2bf(acc[mi][0]); o.y = f2bf(acc[mi][1]);
            o.z = f2bf(acc[mi][2]); o.w = f2bf(acc[mi][3]);
            int hd = (mi - 8) * 16 + l15, key = w * 16 + lg * 4;
            *(ushort4*)(vtb + SWZ(hd * 128 + key * 2, hd)) = o;
        }
    }
    __syncthreads();
    const int b = row0 >> 11, r0b = row0 & 2047;
    #pragma unroll
    for (int i = 0; i < 4; ++i) {                // Q/K: 1024 granules
        int idx = t + i * 256;
        int r = idx >> 4, g = idx & 15;
        short8 v = *(short8*)(qkb + SWZ16(r * 256 + g * 16, r));
        int c0 = g * 8, m = c0 >> 6, c = c0 & 63;
        *(short8*)&qkv[((size_t)m * NROWS + row0 + r) * HD + c] = v;
    }
    #pragma unroll
    for (int i = 0; i < 2; ++i) {                // V^T: 512 granules
        int idx = t + i * 256;
        int hd = idx >> 3, g = idx & 7;
        short8 v = *(short8*)(vtb + SWZ(hd * 128 + g * 16, hd));
        *(short8*)&vt[((size_t)b * HD + hd) * SEQ + r0b + g * 8] = v;
    }
}

// ------------- kernel 2: causal flash attention, KB=128 pair-steps -------------
// (unchanged from round 4)
__global__ __launch_bounds__(256)
void k_attn(const ushort* __restrict__ q, const ushort* __restrict__ k,
            const ushort* __restrict__ vt, float* __restrict__ out) {
    __shared__ short8 smem[81920 / 16];
    char* base = (char*)smem;                    // 2 x (K 16KB + V 16KB)
    char* pls  = base + 65536;                   // P: 4 waves x 4KB ([16][128] bf16)
    const int t = threadIdx.x, lane = t & 63, w = t >> 6;
    const int l15 = lane & 15, lg = lane >> 4;
    const int b = blockIdx.x & 15, qt = 31 - (blockIdx.x >> 4);  // heavy first
    const int row0 = qt * 64, r0w = row0 + w * 16;
    const ushort* qb = q  + (size_t)b * SEQ * HD;
    const ushort* kb = k  + (size_t)b * SEQ * HD;
    const ushort* vb = vt + (size_t)b * HD * SEQ;
    char* pw = pls + w * 4096;

    short8 qf[2];
    #pragma unroll
    for (int s = 0; s < 2; ++s)
        qf[s] = *(const short8*)&qb[(size_t)(r0w + l15) * HD + s * 32 + lg * 8];

    f32x4 oacc[4];
    #pragma unroll
    for (int h = 0; h < 4; ++h) oacc[h] = (f32x4){0.f, 0.f, 0.f, 0.f};
    float m_ = -INFINITY, l_ = 0.f;

    auto stage = [&](int kt, int buf) {
        char* kbuf = base + buf * 32768;
        char* vbuf = kbuf + 16384;
        int k0 = kt * 128;
        #pragma unroll
        for (int g = 0; g < 4; ++g) {
            int rk = w * 32 + g * 8 + (lane >> 3);          // key row 0..127
            int jk = (lane & 7) ^ (rk & 7);
            gload_lds16(&kb[(size_t)(k0 + rk) * HD + jk * 8],
                        kbuf + (w * 4 + g) * 1024);
            int rv = w * 16 + g * 4 + (lane >> 4);          // hd row 0..63
            int jv = (lane & 15) ^ (rv & 15);
            gload_lds16(&vb[(size_t)rv * SEQ + k0 + jv * 8],
                        vbuf + (w * 4 + g) * 1024);
        }
    };

    const int npair = (qt + 2) >> 1;
    stage(0, 0);
    __syncthreads();
    for (int kt = 0; kt < npair; ++kt) {
        int cur = kt & 1;
        if (kt + 1 < npair) stage(kt + 1, cur ^ 1);
        char* kls = base + cur * 32768;
        char* vls = kls + 16384;
        int k0 = kt * 128;

        f32x4 sa[8];
        #pragma unroll
        for (int a = 0; a < 8; ++a) sa[a] = (f32x4){0.f, 0.f, 0.f, 0.f};
        __builtin_amdgcn_s_setprio(1);
        #pragma unroll
        for (int s = 0; s < 2; ++s)
            #pragma unroll
            for (int a = 0; a < 8; ++a) {
                int r = a * 16 + l15;
                short8 kf = *(short8*)(kls + SWZ(r * 128 + s * 64 + lg * 16, r));
                sa[a] = __builtin_amdgcn_mfma_f32_16x16x32_bf16(kf, qf[s], sa[a], 0, 0, 0);
            }
        __builtin_amdgcn_s_setprio(0);

        if (kt == npair - 1) {                   // causal mask (last pair only)
            int qrow = r0w + l15;
            #pragma unroll
            for (int a = 0; a < 8; ++a)
                #pragma unroll
                for (int r = 0; r < 4; ++r)
                    if (k0 + a * 16 + lg * 4 + r > qrow) sa[a][r] = -INFINITY;
        }

        float smax = -INFINITY;
        #pragma unroll
        for (int a = 0; a < 8; ++a)
            #pragma unroll
            for (int r = 0; r < 4; ++r) smax = fmaxf(smax, sa[a][r]);
        smax = fmaxf(smax, __shfl_xor(smax, 16));
        smax = fmaxf(smax, __shfl_xor(smax, 32));
        if (!__all(smax - m_ <= 8.0f)) {         // T13 defer-max
            float mn   = fmaxf(m_, smax);
            float corr = __builtin_amdgcn_exp2f(m_ - mn);
            l_ *= corr;
            #pragma unroll
            for (int h = 0; h < 4; ++h) oacc[h] *= corr;
            m_ = mn;
        }
        float p[32], ps = 0.f;
        #pragma unroll
        for (int a = 0; a < 8; ++a)
            #pragma unroll
            for (int r = 0; r < 4; ++r) {
                float pv = __builtin_amdgcn_exp2f(sa[a][r] - m_);
                p[a * 4 + r] = pv; ps += pv;
            }
        ps += __shfl_xor(ps, 16);
        ps += __shfl_xor(ps, 32);
        l_ += ps;

        #pragma unroll
        for (int a = 0; a < 8; ++a) {            // P -> per-wave LDS [16][128]
            ushort4 pb;
            pb.x = f2bf(p[a * 4 + 0]); pb.y = f2bf(p[a * 4 + 1]);
            pb.z = f2bf(p[a * 4 + 2]); pb.w = f2bf(p[a * 4 + 3]);
            *(ushort4*)(pw + SWZ16(l15 * 256 + a * 32 + lg * 8, l15)) = pb;
        }

        __builtin_amdgcn_s_setprio(1);
        #pragma unroll
        for (int ki = 0; ki < 4; ++ki) {         // PV over 128 keys
            short8 pf = *(short8*)(pw + SWZ16(l15 * 256 + ki * 64 + lg * 16, l15));
            #pragma unroll
            for (int h = 0; h < 4; ++h) {
                int rr = h * 16 + l15;
                short8 vf = *(short8*)(vls + SWZ16(rr * 256 + ki * 64 + lg * 16, rr));
                oacc[h] = __builtin_amdgcn_mfma_f32_16x16x32_bf16(vf, pf, oacc[h], 0, 0, 0);
            }
        }
        __builtin_amdgcn_s_setprio(0);
        __syncthreads();
    }

    float inv = 1.0f / l_;
    #pragma unroll
    for (int h = 0; h < 4; ++h) {
        f32x4 v = oacc[h] * inv;
        int qr = w * 16 + l15;
        *(f32x4*)(base + SWZ16(qr * 256 + h * 64 + lg * 16, qr)) = v;
    }
    __syncthreads();
    #pragma unroll
    for (int i = 0; i < 4; ++i) {
        int idx = t + i * 256;
        int r = idx >> 4, g = idx & 15;
        f32x4 v = *(f32x4*)(base + SWZ16(r * 256 + g * 16, r));
        *(f32x4*)&out[((size_t)b * SEQ + row0 + r) * HD + g * 4] = v;
    }
}

extern "C" void kernel_launch(void* const* d_in, const int* in_sizes, int n_in,
                              void* d_out, int out_size, void* d_ws, size_t ws_size,
                              hipStream_t stream) {
    const float* x  = (const float*)d_in[0];
    const float* Wq = (const float*)d_in[1];
    const float* Wk = (const float*)d_in[2];
    const float* Wv = (const float*)d_in[3];
    float* out = (float*)d_out;
    ushort* ws = (ushort*)d_ws;
    ushort* wt16 = ws;                                   // 192*1024
    ushort* qk16 = ws + 192 * 1024;                      // 2*NROWS*64 (Q,K)
    ushort* vt16 = qk16 + (size_t)2 * NROWS * HD;        // BATCH*64*2048

    k_transpose_w<<<768, 256, 0, stream>>>(Wq, Wk, Wv, wt16);
    k_qkv_proj  <<<NROWS / 64, 256, 0, stream>>>(x, wt16, qk16, vt16);
    k_attn      <<<BATCH * (SEQ / 64), 256, 0, stream>>>(
                    qk16, qk16 + (size_t)NROWS * HD, vt16, out);
}